// Round 1
// baseline (1993.637 us; speedup 1.0000x reference)
//
#include <hip/hip_runtime.h>
#include <hip/hip_bf16.h>

// FeatureAdaption: conv3x3(256->256,+b1) -> conv3x3(256->72,+b2) = offsets,
// then deformable conv v1 (dg=4, K=9) with wd + ReLU.
// B=8, C=256, H=W=64. All fp32 this round (baseline).
//
// Buffers:
//   d_out is used as scratch for t1 = conv1(x) (same size as final output),
//   then overwritten by the deform kernel. Workspace holds offset buffer +
//   pre-transposed weights (total ~14.8 MB).

#define B_ 8
#define C_ 256
#define H_ 64
#define W_ 64
#define DG 4
#define CG 64
#define KK9 9

// ---------------- weight transpose ----------------
// wt1[(ci*9+k)*256 + co] = w1[co][ci][k]
// wt2[(ci*9+k)*72  + co] = w2[co][ci][k]
// wtd[((g*9+k)*64+c)*256 + o] = wd[o][g*64+c][k]
__global__ __launch_bounds__(256) void transpose_w_kernel(
    const float* __restrict__ w1, const float* __restrict__ w2,
    const float* __restrict__ wd,
    float* __restrict__ wt1, float* __restrict__ wt2, float* __restrict__ wtd) {
  const int N1 = 256 * 256 * 9;        // 589824
  const int N2 = 72 * 256 * 9;         // 165888
  const int N3 = 256 * 256 * 9;        // 589824
  int total = N1 + N2 + N3;
  for (int i = blockIdx.x * 256 + threadIdx.x; i < total; i += gridDim.x * 256) {
    if (i < N1) {
      int d = i;
      int co = d & 255; int rest = d >> 8;
      int k = rest % 9; int ci = rest / 9;
      wt1[d] = w1[(co * 256 + ci) * 9 + k];
    } else if (i < N1 + N2) {
      int d = i - N1;
      int co = d % 72; int rest = d / 72;
      int k = rest % 9; int ci = rest / 9;
      wt2[d] = w2[(co * 256 + ci) * 9 + k];
    } else {
      int d = i - N1 - N2;
      int o = d & 255; int rest = d >> 8;
      int c = rest & 63; int gk = rest >> 6;
      int k = gk % 9; int g = gk / 9;
      wtd[d] = wd[o * 2304 + (g * 64 + c) * 9 + k];
    }
  }
}

// ---------------- direct 3x3 conv (SAME), CI=256 ----------------
// Block: 256 threads. Tile: 8 rows x 64 cols, CO_BLK output channels.
// thread t: col = t&63, row-pair rp = t>>6 (rows rp*2, rp*2+1).
// CI staged 8 at a time in LDS with halo; weights staged per chunk.
template <int CO_BLK>
__global__ __launch_bounds__(256) void conv3x3_kernel(
    const float* __restrict__ in,     // [B][256][64][64]
    const float* __restrict__ wt,     // [(ci*9+k)*CO_total + co]
    const float* __restrict__ bias,   // [CO_total]
    float* __restrict__ out,          // [B][CO_total][64][64]
    int CO_total, int nCoBlk) {
  int bid = blockIdx.x;
  int cob = bid % nCoBlk; int rem = bid / nCoBlk;
  int rt = rem & 7; int b = rem >> 3;
  int r0g = rt * 8;
  int co0 = cob * CO_BLK;

  __shared__ float xs[8 * 10 * 66];          // [ci][y(10)][x(66)]
  __shared__ float ws[8 * 9 * CO_BLK];       // [ci][k][co]

  int t = threadIdx.x;
  int col = t & 63;
  int rp = t >> 6;       // 0..3

  float acc0[CO_BLK], acc1[CO_BLK];
#pragma unroll
  for (int j = 0; j < CO_BLK; ++j) { acc0[j] = 0.f; acc1[j] = 0.f; }

  for (int cc = 0; cc < 32; ++cc) {          // 32 chunks of 8 input channels
    // stage x tile (with zero halo)
    for (int e = t; e < 8 * 660; e += 256) {
      int ci = e / 660; int r2 = e - ci * 660;
      int yy = r2 / 66; int xx = r2 - yy * 66;
      int gy = r0g + yy - 1; int gx = xx - 1;
      float v = 0.f;
      if (gy >= 0 && gy < 64 && gx >= 0 && gx < 64)
        v = in[(((size_t)b * 256 + cc * 8 + ci) << 12) + gy * 64 + gx];
      xs[e] = v;
    }
    // stage weights
    for (int e = t; e < 72 * CO_BLK; e += 256) {
      int ci = e / (9 * CO_BLK); int r2 = e - ci * 9 * CO_BLK;
      int k = r2 / CO_BLK; int co = r2 - k * CO_BLK;
      ws[e] = wt[((cc * 8 + ci) * 9 + k) * CO_total + co0 + co];
    }
    __syncthreads();

    for (int ci = 0; ci < 8; ++ci) {
#pragma unroll
      for (int k = 0; k < 9; ++k) {
        int ky = k / 3, kx = k - (k / 3) * 3;
        float xv0 = xs[ci * 660 + (rp * 2 + ky) * 66 + col + kx];
        float xv1 = xs[ci * 660 + (rp * 2 + 1 + ky) * 66 + col + kx];
        const float* wrow = &ws[(ci * 9 + k) * CO_BLK];
#pragma unroll
        for (int j = 0; j < CO_BLK; ++j) {
          float w = wrow[j];               // wave-uniform LDS broadcast
          acc0[j] += xv0 * w;
          acc1[j] += xv1 * w;
        }
      }
    }
    __syncthreads();
  }

  // epilogue (+bias)
  int r0 = r0g + rp * 2;
#pragma unroll
  for (int j = 0; j < CO_BLK; ++j) {
    float bv = bias[co0 + j];
    size_t base = (((size_t)b * CO_total + co0 + j) << 12);
    out[base + (size_t)r0 * 64 + col] = acc0[j] + bv;
    out[base + (size_t)(r0 + 1) * 64 + col] = acc1[j] + bv;
  }
}

// ---------------- deformable conv + relu ----------------
// Block per (b,h): 256 threads. Output tile: 64 px (one row) x 256 co.
// Per (g,k): stage bilinear samples val[c (64)][px (64)] into LDS,
// then register-tiled einsum: thread = (px-slot t&15 -> 4 px, co-block t>>4 -> 16 co).
__global__ __launch_bounds__(256) void deform_kernel(
    const float* __restrict__ x,      // [B][256][64][64]
    const float* __restrict__ off,    // [B][72][64][64]
    const float* __restrict__ wtd,    // [((g*9+k)*64+c)*256 + o]
    float* __restrict__ out) {        // [B][256][64][64]
  int bh = blockIdx.x;
  int b = bh >> 6; int h = bh & 63;

  __shared__ float vals[64 * 64];     // [c][px]

  int t = threadIdx.x;
  // compute-phase ids
  int slot = t & 15; int cb = t >> 4;
  int px4 = slot * 4; int co0 = cb * 16;
  // stage-phase ids
  int spx = t & 63; int cq = t >> 6;  // cq: which 16-channel group to sample

  float4 acc[16];
#pragma unroll
  for (int j = 0; j < 16; ++j) acc[j] = make_float4(0.f, 0.f, 0.f, 0.f);

  for (int g = 0; g < 4; ++g) {
    for (int k = 0; k < 9; ++k) {
      // ---- stage phase ----
      int ch = g * 18 + k * 2;
      const float* offp = off + (((size_t)b * 72 + ch) << 12) + h * 64;
      float dy = offp[spx];
      float dx = offp[4096 + spx];
      int ky = k / 3, kx = k - ky * 3;
      float py = (float)(h + ky - 1) + dy;
      float pxv = (float)(spx + kx - 1) + dx;
      float y0f = floorf(py), x0f = floorf(pxv);
      float wy1 = py - y0f, wx1 = pxv - x0f;
      float wy0 = 1.f - wy1, wx0 = 1.f - wx1;
      int y0 = (int)y0f, x0i = (int)x0f;
      int y1 = y0 + 1, x1i = x0i + 1;
      bool vy0 = (y0 >= 0) & (y0 < 64);
      bool vy1 = (y1 >= 0) & (y1 < 64);
      bool vx0 = (x0i >= 0) & (x0i < 64);
      bool vx1 = (x1i >= 0) & (x1i < 64);
      float w00 = (vy0 & vx0) ? wy0 * wx0 : 0.f;
      float w01 = (vy0 & vx1) ? wy0 * wx1 : 0.f;
      float w10 = (vy1 & vx0) ? wy1 * wx0 : 0.f;
      float w11 = (vy1 & vx1) ? wy1 * wx1 : 0.f;
      int yc0 = min(max(y0, 0), 63), yc1 = min(max(y1, 0), 63);
      int xc0 = min(max(x0i, 0), 63), xc1 = min(max(x1i, 0), 63);
      int o00 = yc0 * 64 + xc0, o01 = yc0 * 64 + xc1;
      int o10 = yc1 * 64 + xc0, o11 = yc1 * 64 + xc1;
      const float* xb = x + (((size_t)(b * 4 + g) * 64 + cq * 16) << 12);
      float* vrow = &vals[cq * 16 * 64 + spx];
#pragma unroll 4
      for (int c2 = 0; c2 < 16; ++c2) {
        float v = w00 * xb[o00] + w01 * xb[o01] + w10 * xb[o10] + w11 * xb[o11];
        vrow[c2 * 64] = v;
        xb += 4096;
      }
      __syncthreads();

      // ---- compute phase ----
      const float* wp = wtd + ((size_t)(g * 9 + k) * 64) * 256 + co0;
#pragma unroll 2
      for (int c = 0; c < 64; ++c) {
        float4 v = *(const float4*)&vals[c * 64 + px4];
        const float* w = wp + c * 256;
#pragma unroll
        for (int j = 0; j < 16; ++j) {
          float wj = w[j];                 // coalesced, L2-hot
          acc[j].x += v.x * wj;
          acc[j].y += v.y * wj;
          acc[j].z += v.z * wj;
          acc[j].w += v.w * wj;
        }
      }
      __syncthreads();
    }
  }

  // epilogue: relu + store (4 px contiguous -> float4)
#pragma unroll
  for (int j = 0; j < 16; ++j) {
    float4 r;
    r.x = fmaxf(acc[j].x, 0.f);
    r.y = fmaxf(acc[j].y, 0.f);
    r.z = fmaxf(acc[j].z, 0.f);
    r.w = fmaxf(acc[j].w, 0.f);
    float4* outp = (float4*)(out + (((size_t)b * 256 + co0 + j) << 12) + h * 64 + px4);
    *outp = r;
  }
}

extern "C" void kernel_launch(void* const* d_in, const int* in_sizes, int n_in,
                              void* d_out, int out_size, void* d_ws, size_t ws_size,
                              hipStream_t stream) {
  const float* x  = (const float*)d_in[0];
  const float* w1 = (const float*)d_in[1];
  const float* b1 = (const float*)d_in[2];
  const float* w2 = (const float*)d_in[3];
  const float* b2 = (const float*)d_in[4];
  const float* wd = (const float*)d_in[5];
  float* out = (float*)d_out;

  float* ws = (float*)d_ws;
  float* off_buf = ws;                         // 8*72*64*64      = 2,359,296
  float* wt1 = off_buf + 2359296;              // 256*256*9       =   589,824
  float* wt2 = wt1 + 589824;                   // 72*256*9        =   165,888
  float* wtd = wt2 + 165888;                   // 256*256*9       =   589,824
                                               // total 14.8 MB

  transpose_w_kernel<<<2048, 256, 0, stream>>>(w1, w2, wd, wt1, wt2, wtd);

  // conv1: x -> t1 (stored in d_out), 256 channels, CO_BLK=32 -> 8 co blocks
  conv3x3_kernel<32><<<8 * 8 * 8, 256, 0, stream>>>(x, wt1, b1, out, 256, 8);

  // conv2: t1 -> offsets, 72 channels, CO_BLK=24 -> 3 co blocks
  conv3x3_kernel<24><<<8 * 8 * 3, 256, 0, stream>>>(out, wt2, b2, off_buf, 72, 3);

  // deform conv + relu: overwrites d_out
  deform_kernel<<<8 * 64, 256, 0, stream>>>(x, off_buf, wtd, out);
}

// Round 2
// 707.341 us; speedup vs baseline: 2.8185x; 2.8185x over previous
//
#include <hip/hip_runtime.h>
#include <hip/hip_bf16.h>

// FeatureAdaption on MI355X, round 2: all three convs as bf16 MFMA.
// conv3x3(256->256,+b1) -> conv3x3(256->72,+b2) = offsets -> deform conv v1 + ReLU.
// B=8, C=256, H=W=64, dg=4, K=9.
//
// Unified kernel: block = (b, h-row), M=64 px, K=2304 processed as 36 iters of
// (tap, 64-channel chunk); stage 64x64 bf16 val tile in LDS (pitch 72 ushorts),
// MFMA 16x16x32 bf16, B-operand (weights, co-major [co][2304] bf16) from global
// (L2-hot, 1.18 MB shared across all blocks).

typedef __attribute__((ext_vector_type(8))) short bf16x8;
typedef __attribute__((ext_vector_type(4))) float f32x4;

static __device__ __forceinline__ ushort f2bf(float f) {
  __hip_bfloat16 h = __float2bfloat16(f);
  return *reinterpret_cast<ushort*>(&h);
}

// ---------------- weight prep: transpose + bf16 convert ----------------
// K order: conv  -> k = (kk*4 + chunk)*64 + cc   (ci = chunk*64+cc, kk = 3x3 tap)
//          deform-> k = (g*9 + kk)*64 + c        (c  = channel in group)
__global__ __launch_bounds__(256) void prep_weights(
    const float* __restrict__ w1, const float* __restrict__ w2,
    const float* __restrict__ wd,
    ushort* __restrict__ wt1b, ushort* __restrict__ wt2b,
    ushort* __restrict__ wtdb) {
  const int N1 = 256 * 2304, N2 = 128 * 2304, N3 = 256 * 2304;
  int total = N1 + N2 + N3;
  for (int i = blockIdx.x * 256 + threadIdx.x; i < total; i += gridDim.x * 256) {
    if (i < N1) {
      int co = i / 2304, r = i % 2304;
      int ti = r >> 6, cc = r & 63;
      int kk = ti >> 2, chunk = ti & 3;
      wt1b[i] = f2bf(w1[(co * 256 + chunk * 64 + cc) * 9 + kk]);
    } else if (i < N1 + N2) {
      int d = i - N1;
      int co = d / 2304, r = d % 2304;
      int ti = r >> 6, cc = r & 63;
      int kk = ti >> 2, chunk = ti & 3;
      wt2b[d] = (co < 72) ? f2bf(w2[(co * 256 + chunk * 64 + cc) * 9 + kk])
                          : (ushort)0;
    } else {
      int d = i - N1 - N2;
      int co = d / 2304, r = d % 2304;
      int ti = r >> 6, c = r & 63;
      int g = ti / 9, kk = ti - g * 9;
      wtdb[d] = f2bf(wd[(co * 256 + g * 64 + c) * 9 + kk]);
    }
  }
}

// ---------------- unified MFMA kernel ----------------
// MODE 0: direct 3x3 conv (SAME) over 256 input channels.
// MODE 1: deformable bilinear sampling (dg=4, K=9), offsets from `off`.
// SPLIT_M=false: 4 waves split N (co), each wave co-width NFR*16, full M=64.
// SPLIT_M=true : 4 waves split M (px), co0=0 for all waves (small-N conv2).
template <int MODE, int MFR, int NFR, bool SPLIT_M, bool RELU, bool HASBIAS>
__global__ __launch_bounds__(256) void fa_mfma_kernel(
    const float* __restrict__ in,    // x (MODE1 / conv1) or t1 (conv2)
    const float* __restrict__ off,   // offsets [B][72][64][64] (MODE 1)
    const ushort* __restrict__ wB,   // [co][2304] bf16
    const float* __restrict__ bias,
    float* __restrict__ out,         // [B][co_total][64][64]
    int co_total, int co_write) {
  int bh = blockIdx.x;
  int b = bh >> 6, h = bh & 63;
  int t = threadIdx.x;
  int wave = t >> 6, lane = t & 63;
  int spx = t & 63, cq = t >> 6;   // stage ids: px, 16-channel quarter

  __shared__ ushort vs[64 * 72];   // [px][c], pitch 72 (A-read b128 bank-optimal)

  f32x4 acc[MFR][NFR];
#pragma unroll
  for (int i = 0; i < MFR; ++i)
#pragma unroll
    for (int j = 0; j < NFR; ++j) acc[i][j] = (f32x4){0.f, 0.f, 0.f, 0.f};

  const int co0w = SPLIT_M ? 0 : wave * (NFR * 16);
  const int m0w  = SPLIT_M ? wave * (MFR * 16) : 0;
  const int ml = lane & 15, kc = lane >> 4;

  for (int ti = 0; ti < 36; ++ti) {
    // ---- compute 16 bf16 samples (pure registers) ----
    uint pk[8];
    if (MODE == 0) {
      int kk = ti >> 2, chunk = ti & 3;
      int ky = kk / 3, kx = kk - ky * 3;
      int gy = h + ky - 1, gx = spx + kx - 1;
      bool inb = (gy >= 0) & (gy < 64) & (gx >= 0) & (gx < 64);
      const float* ip =
          in + (((size_t)b * 256 + chunk * 64 + cq * 16) << 12) + gy * 64 + gx;
#pragma unroll
      for (int c2 = 0; c2 < 16; c2 += 2) {
        float v0 = inb ? ip[(size_t)c2 << 12] : 0.f;
        float v1 = inb ? ip[(size_t)(c2 + 1) << 12] : 0.f;
        pk[c2 >> 1] = (uint)f2bf(v0) | ((uint)f2bf(v1) << 16);
      }
    } else {
      int g = ti / 9, kk = ti - g * 9;
      int ch = g * 18 + kk * 2;
      const float* offp = off + (((size_t)b * 72 + ch) << 12) + h * 64;
      float dy = offp[spx];
      float dx = offp[4096 + spx];
      int ky = kk / 3, kx = kk - ky * 3;
      float py = (float)(h + ky - 1) + dy;
      float pxv = (float)(spx + kx - 1) + dx;
      float y0f = floorf(py), x0f = floorf(pxv);
      float wy1 = py - y0f, wx1 = pxv - x0f;
      float wy0 = 1.f - wy1, wx0 = 1.f - wx1;
      int y0 = (int)y0f, x0i = (int)x0f;
      int y1 = y0 + 1, x1i = x0i + 1;
      bool vy0 = (y0 >= 0) & (y0 < 64);
      bool vy1 = (y1 >= 0) & (y1 < 64);
      bool vx0 = (x0i >= 0) & (x0i < 64);
      bool vx1 = (x1i >= 0) & (x1i < 64);
      float w00 = (vy0 & vx0) ? wy0 * wx0 : 0.f;
      float w01 = (vy0 & vx1) ? wy0 * wx1 : 0.f;
      float w10 = (vy1 & vx0) ? wy1 * wx0 : 0.f;
      float w11 = (vy1 & vx1) ? wy1 * wx1 : 0.f;
      int yc0 = min(max(y0, 0), 63), yc1 = min(max(y1, 0), 63);
      int xc0 = min(max(x0i, 0), 63), xc1 = min(max(x1i, 0), 63);
      int o00 = yc0 * 64 + xc0, o01 = yc0 * 64 + xc1;
      int o10 = yc1 * 64 + xc0, o11 = yc1 * 64 + xc1;
      const float* xb = in + (((size_t)(b * 4 + g) * 64 + cq * 16) << 12);
#pragma unroll
      for (int c2 = 0; c2 < 16; c2 += 2) {
        const float* x0p = xb + ((size_t)c2 << 12);
        const float* x1p = xb + ((size_t)(c2 + 1) << 12);
        float v0 = w00 * x0p[o00] + w01 * x0p[o01] + w10 * x0p[o10] + w11 * x0p[o11];
        float v1 = w00 * x1p[o00] + w01 * x1p[o01] + w10 * x1p[o10] + w11 * x1p[o11];
        pk[c2 >> 1] = (uint)f2bf(v0) | ((uint)f2bf(v1) << 16);
      }
    }

    __syncthreads();  // previous iter's MFMA reads of vs complete
    *(uint4*)&vs[spx * 72 + cq * 16] = *(uint4*)&pk[0];
    *(uint4*)&vs[spx * 72 + cq * 16 + 8] = *(uint4*)&pk[4];
    __syncthreads();

    // ---- MFMA: 2 K-steps of 32 ----
#pragma unroll
    for (int ks = 0; ks < 2; ++ks) {
      bf16x8 a[MFR], bq[NFR];
#pragma unroll
      for (int mf = 0; mf < MFR; ++mf) {
        int px = m0w + mf * 16 + ml;
        a[mf] = *(const bf16x8*)&vs[px * 72 + ks * 32 + kc * 8];
      }
#pragma unroll
      for (int nf = 0; nf < NFR; ++nf) {
        int co = co0w + nf * 16 + ml;
        bq[nf] = *(const bf16x8*)&wB[(size_t)co * 2304 + ti * 64 + ks * 32 + kc * 8];
      }
#pragma unroll
      for (int mf = 0; mf < MFR; ++mf)
#pragma unroll
        for (int nf = 0; nf < NFR; ++nf)
          acc[mf][nf] =
              __builtin_amdgcn_mfma_f32_16x16x32_bf16(a[mf], bq[nf], acc[mf][nf], 0, 0, 0);
    }
  }

  // ---- epilogue: D layout col=lane&15 (co), row=(lane>>4)*4+ri (px) ----
  int rq = lane >> 4;
#pragma unroll
  for (int nf = 0; nf < NFR; ++nf) {
    int co = co0w + nf * 16 + ml;
    if (co < co_write) {
      float bv = HASBIAS ? bias[co] : 0.f;
      float* op = out + (((size_t)b * co_total + co) << 12) + h * 64;
#pragma unroll
      for (int mf = 0; mf < MFR; ++mf) {
#pragma unroll
        for (int ri = 0; ri < 4; ++ri) {
          int px = m0w + mf * 16 + rq * 4 + ri;
          float v = acc[mf][nf][ri] + bv;
          if (RELU) v = fmaxf(v, 0.f);
          op[px] = v;
        }
      }
    }
  }
}

extern "C" void kernel_launch(void* const* d_in, const int* in_sizes, int n_in,
                              void* d_out, int out_size, void* d_ws, size_t ws_size,
                              hipStream_t stream) {
  const float* x  = (const float*)d_in[0];
  const float* w1 = (const float*)d_in[1];
  const float* b1 = (const float*)d_in[2];
  const float* w2 = (const float*)d_in[3];
  const float* b2 = (const float*)d_in[4];
  const float* wd = (const float*)d_in[5];
  float* out = (float*)d_out;

  float* wsf = (float*)d_ws;
  float* off_buf = wsf;                              // 8*72*64*64 = 2,359,296 f
  ushort* wt1b = (ushort*)(wsf + 2359296);           // 256*2304
  ushort* wt2b = wt1b + 256 * 2304;                  // 128*2304 (72 used, rest 0)
  ushort* wtdb = wt2b + 128 * 2304;                  // 256*2304  -> total ~12.4 MB

  prep_weights<<<2048, 256, 0, stream>>>(w1, w2, wd, wt1b, wt2b, wtdb);

  // conv1: x -> t1 (in d_out), co=256, 4 waves split N (4x4 frags)
  fa_mfma_kernel<0, 4, 4, false, false, true>
      <<<512, 256, 0, stream>>>(x, nullptr, wt1b, b1, out, 256, 256);

  // conv2: t1 -> offsets, co=72 (padded 80), 4 waves split M (1x5 frags)
  fa_mfma_kernel<0, 1, 5, true, false, true>
      <<<512, 256, 0, stream>>>(out, nullptr, wt2b, b2, off_buf, 72, 72);

  // deform + relu: x,offsets -> d_out, co=256
  fa_mfma_kernel<1, 4, 4, false, true, false>
      <<<512, 256, 0, stream>>>(x, off_buf, wtdb, nullptr, out, 256, 256);
}

// Round 3
// 209.011 us; speedup vs baseline: 9.5384x; 3.3842x over previous
//
#include <hip/hip_runtime.h>
#include <hip/hip_bf16.h>

// FeatureAdaption R3: register-direct A-fragments (M-split waves), channel-last
// bf16 x, async double-buffered B staging via global_load_lds.
// conv1(256->256)+b1 -> conv2(256->72)+b2 = offsets -> deform conv v1 + ReLU.
// B=8, C=256, H=W=64, dg=4, K=9.

typedef __attribute__((ext_vector_type(8))) short bf16x8;
typedef __attribute__((ext_vector_type(4))) float f32x4;

static __device__ __forceinline__ ushort f2bf(float f) {
  __hip_bfloat16 h = __float2bfloat16(f);
  return *reinterpret_cast<ushort*>(&h);
}
static __device__ __forceinline__ float bf2f(ushort u) {
  union { uint u32; float f; } cv;
  cv.u32 = ((uint)u) << 16;
  return cv.f;
}

// ---------------- weight prep (same K-order as R2, verified) ----------------
// conv  : k = (kk*4 + chunk)*64 + cc   (ci = chunk*64+cc)
// deform: k = (g*9 + kk)*64 + c
__global__ __launch_bounds__(256) void prep_weights(
    const float* __restrict__ w1, const float* __restrict__ w2,
    const float* __restrict__ wd,
    ushort* __restrict__ wt1b, ushort* __restrict__ wt2b,
    ushort* __restrict__ wtdb) {
  const int N1 = 256 * 2304, N2 = 128 * 2304, N3 = 256 * 2304;
  int total = N1 + N2 + N3;
  for (int i = blockIdx.x * 256 + threadIdx.x; i < total; i += gridDim.x * 256) {
    if (i < N1) {
      int co = i / 2304, r = i % 2304;
      int ti = r >> 6, cc = r & 63;
      int kk = ti >> 2, chunk = ti & 3;
      wt1b[i] = f2bf(w1[(co * 256 + chunk * 64 + cc) * 9 + kk]);
    } else if (i < N1 + N2) {
      int d = i - N1;
      int co = d / 2304, r = d % 2304;
      int ti = r >> 6, cc = r & 63;
      int kk = ti >> 2, chunk = ti & 3;
      wt2b[d] = (co < 72) ? f2bf(w2[(co * 256 + chunk * 64 + cc) * 9 + kk])
                          : (ushort)0;
    } else {
      int d = i - N1 - N2;
      int co = d / 2304, r = d % 2304;
      int ti = r >> 6, c = r & 63;
      int g = ti / 9, kk = ti - g * 9;
      wtdb[d] = f2bf(wd[(co * 256 + g * 64 + c) * 9 + kk]);
    }
  }
}

// ---------------- x -> channel-last grouped bf16 ----------------
// xt[((b*4+g)*4096 + y*64 + xx)*64 + c] = bf16(x[b][g*64+c][y][xx])
__global__ __launch_bounds__(256) void transpose_x(
    const float* __restrict__ x, ushort* __restrict__ xt) {
  int id = blockIdx.x;              // 2048 = (b*4+g)*64 + y
  int y = id & 63, bg = id >> 6;
  int c = threadIdx.x & 63, xi = threadIdx.x >> 6;
  const float* ip = x + (((size_t)bg) << 18) + ((size_t)c << 12) + y * 64;
  ushort* op = xt + (((size_t)bg) << 18) + (size_t)y * 4096 + c;
#pragma unroll
  for (int j = 0; j < 16; ++j) {
    int xx = xi * 16 + j;
    op[(size_t)xx * 64] = f2bf(ip[xx]);   // lanes = consecutive c -> coalesced
  }
}

// ---------------- unified MFMA kernel, v2 ----------------
// Block = (b,h) [XCD-swizzled], 4 waves; wave w owns px rows [w*16, w*16+16),
// full N = NFR*16 outputs. A-frags built in registers from channel-last bf16.
// B double-buffered in LDS (pitch 144B), staged async via global_load_lds.
template <int MODE, int NFR, int CO_TILE, bool RELU, bool HASBIAS, bool OUT_CHLAST>
__global__ __launch_bounds__(256, 2) void fa_mfma2(
    const ushort* __restrict__ inT,  // [bg][4096 pix][64 c] bf16
    const float* __restrict__ off,   // [B][72][64][64] f32 (MODE 1)
    const ushort* __restrict__ wB,   // [co][2304] bf16
    const float* __restrict__ bias,
    void* __restrict__ outp,
    int co_total, int co_write) {
  constexpr int NCALLS = (CO_TILE * 144 + 4095) / 4096;
  constexpr int BUFN = NCALLS * 2048;          // ushorts per buffer (4KB/call)
  __shared__ __align__(16) ushort Blds[2][BUFN];

  int id = blockIdx.x;
  int bh = (id & 7) * 64 + (id >> 3);          // XCD swizzle (512 = 8*64)
  int b = bh >> 6, h = bh & 63;
  int t = threadIdx.x;
  int wave = t >> 6, lane = t & 63;
  int ml = lane & 15, kc = lane >> 4;
  int px = wave * 16 + ml;                     // A row this lane feeds

  // stage addressing: LDS is linear; byte dest = m*4096 + t*16 maps to
  // row co = dest/144, col r = dest%144 (r is a multiple of 16; r==128 -> pad)
  int rb_i[NCALLS];
#pragma unroll
  for (int m = 0; m < NCALLS; ++m) {
    int dest = m * 4096 + t * 16;
    int co = dest / 144;
    int r = dest - co * 144;
    rb_i[m] = co * 4608 + (r >= 128 ? 0 : r);  // bytes into wB (minus ti part)
  }
  const char* wBb = (const char*)wB;

  auto stage = [&](int ti, int bufsel) {
#pragma unroll
    for (int m = 0; m < NCALLS; ++m) {
      const void* src = (const void*)(wBb + (rb_i[m] + ti * 128));
      ushort* dst = &Blds[bufsel][m * 2048 + wave * 512];
      __builtin_amdgcn_global_load_lds(
          (const __attribute__((address_space(1))) void*)src,
          (__attribute__((address_space(3))) void*)dst, 16, 0, 0);
    }
  };

  f32x4 acc[NFR];
#pragma unroll
  for (int j = 0; j < NFR; ++j) acc[j] = (f32x4){0.f, 0.f, 0.f, 0.f};

  stage(0, 0);
  __syncthreads();

  for (int ti = 0; ti < 36; ++ti) {
    int cur = ti & 1;
    if (ti < 35) stage(ti + 1, cur ^ 1);

    // ---- A fragments in registers ----
    bf16x8 a0, a1;
    if (MODE == 0) {
      int kk = ti >> 2, chunk = ti & 3;
      int ky = kk / 3, kx = kk - ky * 3;
      int gy = h + ky - 1, gx = px + kx - 1;
      bool inb = (gy >= 0) & (gy < 64) & (gx >= 0) & (gx < 64);
      const ushort* p =
          inT + ((((size_t)(b * 4 + chunk) << 12) + gy * 64 + gx) << 6) + kc * 8;
      bf16x8 z = {0, 0, 0, 0, 0, 0, 0, 0};
      a0 = inb ? *(const bf16x8*)p : z;
      a1 = inb ? *(const bf16x8*)(p + 32) : z;
    } else {
      int g = ti / 9, kk = ti - g * 9;
      int ky = kk / 3, kx = kk - ky * 3;
      const float* offp = off + (((size_t)b * 72 + g * 18 + kk * 2) << 12) + h * 64;
      float dy = offp[px];
      float dx = offp[4096 + px];
      float py = (float)(h + ky - 1) + dy;
      float pxf = (float)(px + kx - 1) + dx;
      float y0f = floorf(py), x0f = floorf(pxf);
      float wy1 = py - y0f, wx1 = pxf - x0f;
      float wy0 = 1.f - wy1, wx0 = 1.f - wx1;
      int y0 = (int)y0f, x0i = (int)x0f;
      int y1 = y0 + 1, x1i = x0i + 1;
      bool vy0 = (y0 >= 0) & (y0 < 64);
      bool vy1 = (y1 >= 0) & (y1 < 64);
      bool vx0 = (x0i >= 0) & (x0i < 64);
      bool vx1 = (x1i >= 0) & (x1i < 64);
      float w00 = (vy0 & vx0) ? wy0 * wx0 : 0.f;
      float w01 = (vy0 & vx1) ? wy0 * wx1 : 0.f;
      float w10 = (vy1 & vx0) ? wy1 * wx0 : 0.f;
      float w11 = (vy1 & vx1) ? wy1 * wx1 : 0.f;
      int yc0 = min(max(y0, 0), 63), yc1 = min(max(y1, 0), 63);
      int xc0 = min(max(x0i, 0), 63), xc1 = min(max(x1i, 0), 63);
      const ushort* base = inT + (((size_t)(b * 4 + g)) << 18) + kc * 8;
      const ushort* p00 = base + ((yc0 * 64 + xc0) << 6);
      const ushort* p01 = base + ((yc0 * 64 + xc1) << 6);
      const ushort* p10 = base + ((yc1 * 64 + xc0) << 6);
      const ushort* p11 = base + ((yc1 * 64 + xc1) << 6);
#pragma unroll
      for (int ks = 0; ks < 2; ++ks) {
        bf16x8 r00 = *(const bf16x8*)(p00 + ks * 32);
        bf16x8 r01 = *(const bf16x8*)(p01 + ks * 32);
        bf16x8 r10 = *(const bf16x8*)(p10 + ks * 32);
        bf16x8 r11 = *(const bf16x8*)(p11 + ks * 32);
        uint pk[4];
#pragma unroll
        for (int jj = 0; jj < 4; ++jj) {
          float v0 = w00 * bf2f((ushort)r00[2 * jj]) + w01 * bf2f((ushort)r01[2 * jj]) +
                     w10 * bf2f((ushort)r10[2 * jj]) + w11 * bf2f((ushort)r11[2 * jj]);
          float v1 = w00 * bf2f((ushort)r00[2 * jj + 1]) + w01 * bf2f((ushort)r01[2 * jj + 1]) +
                     w10 * bf2f((ushort)r10[2 * jj + 1]) + w11 * bf2f((ushort)r11[2 * jj + 1]);
          pk[jj] = (uint)f2bf(v0) | ((uint)f2bf(v1) << 16);
        }
        bf16x8 av;
        av[0] = (short)(pk[0] & 0xffff); av[1] = (short)(pk[0] >> 16);
        av[2] = (short)(pk[1] & 0xffff); av[3] = (short)(pk[1] >> 16);
        av[4] = (short)(pk[2] & 0xffff); av[5] = (short)(pk[2] >> 16);
        av[6] = (short)(pk[3] & 0xffff); av[7] = (short)(pk[3] >> 16);
        if (ks == 0) a0 = av; else a1 = av;
      }
    }

    // ---- MFMA from LDS-resident B ----
#pragma unroll
    for (int ks = 0; ks < 2; ++ks) {
      bf16x8 av = ks ? a1 : a0;
#pragma unroll
      for (int nf = 0; nf < NFR; ++nf) {
        bf16x8 bq = *(const bf16x8*)&Blds[cur][(nf * 16 + ml) * 72 + ks * 32 + kc * 8];
        acc[nf] = __builtin_amdgcn_mfma_f32_16x16x32_bf16(av, bq, acc[nf], 0, 0, 0);
      }
    }

    if (ti < 35) __syncthreads();  // next buffer landed; cur free for overwrite
  }

  // ---- epilogue: D col = lane&15 (co), row = (lane>>4)*4 + ri (px) ----
  int rq = lane >> 4;
#pragma unroll
  for (int nf = 0; nf < NFR; ++nf) {
    int co = nf * 16 + ml;
    if (co < co_write) {
      float bv = HASBIAS ? bias[co] : 0.f;
      if (OUT_CHLAST) {
        // bf16 channel-last grouped (feeds conv2 as inT)
        int g_out = co >> 6, ci = co & 63;
        ushort* op = (ushort*)outp +
                     ((((size_t)(b * 4 + g_out) << 12) + h * 64) << 6) + ci;
#pragma unroll
        for (int ri = 0; ri < 4; ++ri) {
          int pxe = wave * 16 + rq * 4 + ri;
          float v = acc[nf][ri] + bv;
          if (RELU) v = fmaxf(v, 0.f);
          op[(size_t)pxe << 6] = f2bf(v);
        }
      } else {
        float* op = (float*)outp + (((size_t)b * co_total + co) << 12) + h * 64;
#pragma unroll
        for (int ri = 0; ri < 4; ++ri) {
          int pxe = wave * 16 + rq * 4 + ri;
          float v = acc[nf][ri] + bv;
          if (RELU) v = fmaxf(v, 0.f);
          op[pxe] = v;
        }
      }
    }
  }
}

extern "C" void kernel_launch(void* const* d_in, const int* in_sizes, int n_in,
                              void* d_out, int out_size, void* d_ws, size_t ws_size,
                              hipStream_t stream) {
  const float* x  = (const float*)d_in[0];
  const float* w1 = (const float*)d_in[1];
  const float* b1 = (const float*)d_in[2];
  const float* w2 = (const float*)d_in[3];
  const float* b2 = (const float*)d_in[4];
  const float* wd = (const float*)d_in[5];

  char* wsb = (char*)d_ws;
  float*  off_buf = (float*)wsb;                        //  9,437,184 B
  ushort* xt      = (ushort*)(wsb + 9437184);           // 16,777,216 B
  ushort* wt1b    = (ushort*)(wsb + 26214400);          //  1,179,648 B
  ushort* wt2b    = (ushort*)(wsb + 27394048);          //    589,824 B
  ushort* wtdb    = (ushort*)(wsb + 27983872);          //  1,179,648 B -> 27.8 MB

  prep_weights<<<2048, 256, 0, stream>>>(w1, w2, wd, wt1b, wt2b, wtdb);
  transpose_x<<<2048, 256, 0, stream>>>(x, xt);

  // conv1: xt -> t1t (bf16 channel-last, stored in d_out)
  fa_mfma2<0, 16, 256, false, true, true>
      <<<512, 256, 0, stream>>>(xt, nullptr, wt1b, b1, d_out, 256, 256);

  // conv2: t1t -> offsets (f32, standard layout)
  fa_mfma2<0, 5, 80, false, true, false>
      <<<512, 256, 0, stream>>>((const ushort*)d_out, nullptr, wt2b, b2,
                                off_buf, 72, 72);

  // deform + relu: xt, offsets -> d_out (f32 final)
  fa_mfma2<1, 16, 256, true, false, false>
      <<<512, 256, 0, stream>>>(xt, off_buf, wtdb, nullptr, d_out, 256, 256);
}